// Round 17
// baseline (499.309 us; speedup 1.0000x reference)
//
#include <hip/hip_runtime.h>
#include <hip/hip_bf16.h>

#define B_ 2
#define Q_ 1024
#define P_ 3072
#define HID_ 4096
#define H_ 32
#define KV_ 8
#define D_ 128
#define S_ 4096
#define NQKV 6144
// 1/sqrt(128) * log2(e)  (softmax runs in log2 domain)
#define QSCALE 0.1275174432f

typedef __attribute__((ext_vector_type(4))) float f32x4;
typedef __attribute__((ext_vector_type(8))) unsigned short u16x8;
typedef __attribute__((ext_vector_type(4))) unsigned short u16x4;
typedef __attribute__((ext_vector_type(8))) __bf16 bf16x8;

__device__ __forceinline__ unsigned short f2bf(float f){
  unsigned u = __builtin_bit_cast(unsigned, f);
  unsigned r = (u + 0x7FFFu + ((u >> 16) & 1u)) >> 16;
  return (unsigned short)r;
}
__device__ __forceinline__ float bf2f(unsigned short h){
  unsigned u = ((unsigned)h) << 16;
  return __builtin_bit_cast(float, u);
}
__device__ __forceinline__ unsigned pk2bf(float lo, float hi){
  unsigned r;
  asm("v_cvt_pk_bf16_f32 %0, %1, %2" : "=v"(r) : "v"(lo), "v"(hi));
  return r;
}
// raw-rate exp2: single v_exp_f32 (libm exp2f is a multi-instr ocml call)
__device__ __forceinline__ float fexp2(float x){
  float r; asm("v_exp_f32 %0, %1" : "=v"(r) : "v"(x)); return r;
}
__device__ __forceinline__ f32x4 mfma16(u16x8 a, u16x8 b, f32x4 c){
  return __builtin_amdgcn_mfma_f32_16x16x32_bf16(
      __builtin_bit_cast(bf16x8, a), __builtin_bit_cast(bf16x8, b), c, 0, 0, 0);
}
typedef const __attribute__((address_space(1))) void* gp1_t;
typedef __attribute__((address_space(3))) void* lp3_t;
__device__ __forceinline__ void gl16(const unsigned short* g, unsigned short* l){
  __builtin_amdgcn_global_load_lds((gp1_t)g, (lp3_t)l, 16, 0, 0);
}

// ---------------- prep_all: convert_w + prep(hs,kc) + cache_vt(vc) + maxw, ONE launch ----
// blocks [0,10240): weight transpose-convert; [10240,12288): hs/kc convert;
// [12288,13056): V transpose; 13056: maxw.
#define N1_ 2097152   // (B*Q*HID)/4
#define N2_ 1572864   // (B*KV*P*D)/4
__global__ __launch_bounds__(256) void prep_all(
    const float* __restrict__ hs, const float* __restrict__ kc,
    const float* __restrict__ vc, const float* __restrict__ qw,
    const float* __restrict__ kw, const float* __restrict__ Wq,
    const float* __restrict__ Wk, const float* __restrict__ Wv,
    const float* __restrict__ Wo, unsigned short* __restrict__ AH,
    unsigned short* __restrict__ Kb, unsigned short* __restrict__ VT,
    unsigned short* __restrict__ WT, unsigned short* __restrict__ WoT,
    float* __restrict__ M){
  __shared__ float tile[64][65];
  __shared__ unsigned short T[128][72];
  __shared__ float sa[4], sb[4];
  int bxg = blockIdx.x;
  int tid = threadIdx.x;
  if(bxg < 10240){
    int x = bxg >> 6;
    int k0 = (bxg & 63) * 64;
    const float* W; int ldn, n_off; unsigned short* dst; int n0;
    if(x < 64)      { W = Wq; ldn = 4096; n_off = 0;    dst = WT;  n0 = x * 64; }
    else if(x < 80) { W = Wk; ldn = 1024; n_off = 4096; dst = WT;  n0 = (x-64) * 64; }
    else if(x < 96) { W = Wv; ldn = 1024; n_off = 5120; dst = WT;  n0 = (x-80) * 64; }
    else            { W = Wo; ldn = 4096; n_off = 0;    dst = WoT; n0 = (x-96) * 64; }
    int r = tid >> 4, c = (tid & 15) * 4;
    #pragma unroll
    for(int j = 0; j < 4; ++j){
      float4 v = *(const float4*)(W + (long)(k0 + r + j*16) * ldn + n0 + c);
      tile[r + j*16][c] = v.x; tile[r + j*16][c+1] = v.y;
      tile[r + j*16][c+2] = v.z; tile[r + j*16][c+3] = v.w;
    }
    __syncthreads();
    #pragma unroll
    for(int j = 0; j < 4; ++j){
      int n = r + j*16;
      long o = (long)(n_off + n0 + n) * 4096 + k0 + c;
      *(u16x4*)(dst + o) = (u16x4){f2bf(tile[c][n]), f2bf(tile[c+1][n]),
                                   f2bf(tile[c+2][n]), f2bf(tile[c+3][n])};
    }
  } else if(bxg < 12288){
    int bx = bxg - 10240;
    const int PD = P_ * D_;
    const long SD = (long)S_ * D_;
    for(int i4 = bx * 256 + tid; i4 < N1_ + N2_; i4 += 2048 * 256){
      if(i4 < N1_){
        long i = (long)i4 * 4;
        float4 x = *(const float4*)(hs + i);
        *(u16x4*)(AH + i) = (u16x4){f2bf(x.x), f2bf(x.y), f2bf(x.z), f2bf(x.w)};
      } else {
        long i = (long)(i4 - N1_) * 4;
        int bkv = (int)(i / PD);
        int rem = (int)(i - (long)bkv * PD);
        long dst = (long)bkv * SD + rem;
        float4 k4 = *(const float4*)(kc + i);
        *(u16x4*)(Kb + dst) = (u16x4){f2bf(k4.x), f2bf(k4.y), f2bf(k4.z), f2bf(k4.w)};
      }
    }
  } else if(bxg < 13056){
    int idx = bxg - 12288;
    int bkv = idx / 48;
    int s0 = (idx % 48) * 64;
    int r = tid >> 2, dblk = (tid & 3) * 32;
    const float* src = vc + ((long)bkv * P_ + s0 + r) * 128 + dblk;
    #pragma unroll
    for(int u = 0; u < 8; ++u){
      float4 v = *(const float4*)(src + u*4);
      T[dblk + u*4 + 0][r] = f2bf(v.x);
      T[dblk + u*4 + 1][r] = f2bf(v.y);
      T[dblk + u*4 + 2][r] = f2bf(v.z);
      T[dblk + u*4 + 3][r] = f2bf(v.w);
    }
    __syncthreads();
    int d = tid >> 1, sh = (tid & 1) * 32;
    unsigned short* dst = VT + ((long)bkv * 128 + d) * S_ + s0 + sh;
    #pragma unroll
    for(int u = 0; u < 4; ++u){
      u16x8 v;
      #pragma unroll
      for(int j = 0; j < 8; ++j) v[j] = T[d][sh + u*8 + j];
      *(u16x8*)(dst + u*8) = v;
    }
  } else {
    float a = (tid < 128) ? fabsf(qw[tid]) : 0.f;
    float b = (tid < 128) ? fabsf(kw[tid]) : 0.f;
    #pragma unroll
    for(int o = 32; o; o >>= 1){
      a = fmaxf(a, __shfl_xor(a, o));
      b = fmaxf(b, __shfl_xor(b, o));
    }
    if((tid & 63) == 0){ sa[tid >> 6] = a; sb[tid >> 6] = b; }
    __syncthreads();
    if(tid == 0){
      float mq = fmaxf(fmaxf(sa[0], sa[1]), fmaxf(sa[2], sa[3]));
      float mk = fmaxf(fmaxf(sb[0], sb[1]), fmaxf(sb[2], sb[3]));
      M[0] = 128.0f * QSCALE * mq * mk * 1.01f + 0.25f;
    }
  }
}

// ---------------- single-plane bf16 GEMM (m97 structure, by-fastest L2 mapping) ----------
__global__ __launch_bounds__(256) void gemm_bf16(
    const unsigned short* __restrict__ Ag, const unsigned short* __restrict__ Bg,
    float* __restrict__ C, int nbx, int ldc){
  __shared__ __align__(16) unsigned short sA[4096], sB[4096];
  int tid = threadIdx.x;
  int nwg = nbx * 16;
  int lin = blockIdx.x;
  int cpx = nwg >> 3;
  int swz = (lin & 7) * cpx + (lin >> 3);   // XCD swizzle (nwg % 8 == 0)
  int by = swz & 15, bx = swz >> 4;         // by fastest: same-B blocks co-resident
  int m0 = by * 128, n0 = bx * 128;
  int lane = tid & 63, w = tid >> 6;
  int lr = lane & 15, lg = lane >> 4;
  int wm = (w >> 1) * 64, wn = (w & 1) * 64;
  int rowi = w * 16 + (lane >> 2);
  int cchunk = ((lane & 3) ^ ((lane >> 3) & 3)) << 3;
  const unsigned short* aP = Ag + (long)(m0 + rowi) * 4096 + cchunk;
  const unsigned short* bP = Bg + (long)(n0 + rowi) * 4096 + cchunk;
  const int step2 = 64 * 4096;
  unsigned short* dA = sA + w * 512;
  unsigned short* dB = sB + w * 512;
  int rdcol = (lg * 8) ^ (((lr >> 1) & 3) << 3);
  f32x4 zero = {0.f,0.f,0.f,0.f};
  f32x4 acc[4][4];
  #pragma unroll
  for(int mi=0;mi<4;++mi)
    #pragma unroll
    for(int ni=0;ni<4;++ni) acc[mi][ni] = zero;

  for(int kt = 0; kt < 128; ++kt){
    int kk = kt * 32;
    __syncthreads();
    gl16(aP + kk, dA);  gl16(aP + step2 + kk, dA + 2048);
    gl16(bP + kk, dB);  gl16(bP + step2 + kk, dB + 2048);
    __syncthreads();
    u16x8 ah[4];
    #pragma unroll
    for(int mi = 0; mi < 4; ++mi)
      ah[mi] = *(const u16x8*)(sA + (wm + mi*16 + lr) * 32 + rdcol);
    #pragma unroll
    for(int ni = 0; ni < 4; ++ni){
      u16x8 bh = *(const u16x8*)(sB + (wn + ni*16 + lr) * 32 + rdcol);
      #pragma unroll
      for(int mi = 0; mi < 4; ++mi)
        acc[mi][ni] = mfma16(ah[mi], bh, acc[mi][ni]);
    }
  }
  #pragma unroll
  for(int mi = 0; mi < 4; ++mi)
    #pragma unroll
    for(int r = 0; r < 4; ++r){
      long rowoff = (long)(m0 + wm + mi*16 + lg*4 + r) * ldc + n0 + wn + lr;
      #pragma unroll
      for(int ni = 0; ni < 4; ++ni)
        C[rowoff + ni*16] = acc[mi][ni][r];
    }
}

// ---------------- fused postprocess Q + KV (one launch) ----------------------------------
__global__ __launch_bounds__(256) void pp_qkv(
    const float* __restrict__ Craw, const float* __restrict__ cosb,
    const float* __restrict__ sinb, const float* __restrict__ qw,
    const float* __restrict__ kw, unsigned short* __restrict__ Qb,
    unsigned short* __restrict__ Kb, unsigned short* __restrict__ VT){
  int rid = blockIdx.x * 4 + (threadIdx.x >> 6);
  int lane = threadIdx.x & 63;
  if(rid < 65536){
    int b = rid >> 15;
    int rem = rid & 32767;
    int q = rem >> 5;
    int h = rem & 31;
    long rowoff = (long)(b * Q_ + q) * NQKV + h * 128;
    float x1 = Craw[rowoff + lane];
    float x2 = Craw[rowoff + 64 + lane];
    float ss = x1*x1 + x2*x2;
    for(int o = 32; o; o >>= 1) ss += __shfl_xor(ss, o);
    float norm = rsqrtf(ss * (1.0f/128.0f) + 1e-6f);
    float xn1 = x1 * norm * qw[lane];
    float xn2 = x2 * norm * qw[64 + lane];
    long co = (long)(b * Q_ + q) * 128;
    float c1 = cosb[co + lane],      s1 = sinb[co + lane];
    float c2 = cosb[co + 64 + lane], s2 = sinb[co + 64 + lane];
    float o1 = (xn1 * c1 - xn2 * s1) * QSCALE;
    float o2 = (xn2 * c2 + xn1 * s2) * QSCALE;
    long dst = ((long)(b * H_ + h) * Q_ + q) * 128;
    Qb[dst + lane] = f2bf(o1);
    Qb[dst + 64 + lane] = f2bf(o2);
  } else {
    int rid2 = rid - 65536;
    int b = rid2 >> 13;
    int rem = rid2 & 8191;
    int q = rem >> 3;
    int kv = rem & 7;
    int bkv = b * KV_ + kv;
    long rowoff = (long)(b * Q_ + q) * NQKV;
    float x1 = Craw[rowoff + 4096 + kv*128 + lane];
    float x2 = Craw[rowoff + 4096 + kv*128 + 64 + lane];
    float ss = x1*x1 + x2*x2;
    for(int o = 32; o; o >>= 1) ss += __shfl_xor(ss, o);
    float norm = rsqrtf(ss * (1.0f/128.0f) + 1e-6f);
    float xn1 = x1 * norm * kw[lane];
    float xn2 = x2 * norm * kw[64 + lane];
    long co = (long)(b * Q_ + q) * 128;
    float c1 = cosb[co + lane],      s1 = sinb[co + lane];
    float c2 = cosb[co + 64 + lane], s2 = sinb[co + 64 + lane];
    long dst = ((long)bkv * S_ + P_ + q) * 128;
    Kb[dst + lane]      = f2bf(xn1 * c1 - xn2 * s1);
    Kb[dst + 64 + lane] = f2bf(xn2 * c2 + xn1 * s2);
    float v1 = Craw[rowoff + 5120 + kv*128 + lane];
    float v2 = Craw[rowoff + 5120 + kv*128 + 64 + lane];
    VT[((long)bkv * 128 + lane) * S_ + P_ + q]      = f2bf(v1);
    VT[((long)bkv * 128 + 64 + lane) * S_ + P_ + q] = f2bf(v2);
  }
}

// ---------------- flash attention: fixed-max, 64 q/wave, QBLK=256, ksplit x2 -------------
#define KVB 32
#define PSL 40
__global__ __launch_bounds__(256, 2) void attn(
    const unsigned short* __restrict__ Qg, const unsigned short* __restrict__ Kg,
    const unsigned short* __restrict__ VTg, const float* __restrict__ Mp,
    unsigned short* __restrict__ po, float* __restrict__ pl){
  __shared__ __align__(16) unsigned short Ks[2][KVB*128];
  __shared__ __align__(16) unsigned short Vs[2][128*KVB];
  __shared__ __align__(16) unsigned short Ps[4][64*PSL];
  int tid = threadIdx.x;
  int qb = blockIdx.x >> 1, sp = blockIdx.x & 1;
  int b = blockIdx.z, h = blockIdx.y, q0 = qb * 256;
  int kvh = h >> 2;
  int w = tid >> 6, lane = tid & 63, lr = lane & 15, lg = lane >> 4;
  int q0w = q0 + w * 64;
  float Mv = Mp[0];
  u16x8 qh[4][4];
  #pragma unroll
  for(int mi = 0; mi < 4; ++mi){
    long qbase = ((long)(b * H_ + h) * Q_ + q0w + mi*16 + lr) * 128;
    #pragma unroll
    for(int c = 0; c < 4; ++c)
      qh[mi][c] = *(const u16x8*)(Qg + qbase + c*32 + lg*8);
  }
  f32x4 minit = {-Mv, -Mv, -Mv, -Mv};
  f32x4 o[4][8];
  #pragma unroll
  for(int mi = 0; mi < 4; ++mi)
    #pragma unroll
    for(int i = 0; i < 8; ++i) o[mi][i] = (f32x4){0.f,0.f,0.f,0.f};
  float l[4] = {0.f, 0.f, 0.f, 0.f};
  long kb  = (long)(b * KV_ + kvh) * S_ * 128;
  long vb0 = (long)(b * KV_ + kvh) * 128 * (long)S_;
  int T = 104 + 8 * qb;
  int half = T >> 1;
  int t0 = sp ? half : 0;
  int t1 = sp ? T : half;
  int koff[2], voff[2], ldst[2];
  #pragma unroll
  for(int i = 0; i < 2; ++i){
    int L = (w*2 + i)*64 + lane;
    ldst[i] = L * 8;
    int r = L >> 4, c8 = (L & 15) ^ (r & 7);
    koff[i] = r*128 + c8*8;
    // V slot L -> d-pair interleave: d = (L>>3)*2 + (L&1), mem-chunk = (L>>1)&3
    int d = ((L >> 3) << 1) | (L & 1);
    int sm = (L >> 1) & 3;
    int g = (d & 3) ^ ((d >> 2) & 3);
    voff[i] = d * S_ + ((sm ^ g) << 3);
  }
  {
    const unsigned short* kg = Kg + kb + (long)t0 * (KVB*128);
    const unsigned short* vg = VTg + vb0 + t0 * KVB;
    #pragma unroll
    for(int i = 0; i < 2; ++i){
      gl16(kg + koff[i], &Ks[t0 & 1][ldst[i]]);
      gl16(vg + voff[i], &Vs[t0 & 1][ldst[i]]);
    }
  }
  __syncthreads();

  int lr7 = lr & 7;
  int gread = (lr & 3) ^ ((lr >> 2) & 3);   // g(d) for d = ni*16+lr (ni-independent)
  for(int t = t0; t < t1; ++t){
    int cur = t & 1;
    if(t + 1 < t1){
      int s1 = (t + 1) * KVB;
      const unsigned short* kg = Kg + kb + (long)s1 * 128;
      const unsigned short* vg = VTg + vb0 + s1;
      #pragma unroll
      for(int i = 0; i < 2; ++i){
        gl16(kg + koff[i], &Ks[cur^1][ldst[i]]);
        gl16(vg + voff[i], &Vs[cur^1][ldst[i]]);
      }
    }
    int s0 = t * KVB;
    if(s0 <= P_ + q0w + 63){
      // ---- QK^T (swapped): D[key][q], q = lr per lane ----
      f32x4 pacc[4][2];
      #pragma unroll
      for(int mi = 0; mi < 4; ++mi){ pacc[mi][0] = minit; pacc[mi][1] = minit; }
      __builtin_amdgcn_s_setprio(1);
      #pragma unroll
      for(int c = 0; c < 4; ++c)
        #pragma unroll
        for(int ni = 0; ni < 2; ++ni){
          u16x8 kh = *(const u16x8*)(&Ks[cur][(ni*16 + lr)*128 + (((c*4 + lg) ^ lr7) << 3)]);
          #pragma unroll
          for(int mi = 0; mi < 4; ++mi)
            pacc[mi][ni] = mfma16(kh, qh[mi][c], pacc[mi][ni]);
        }
      __builtin_amdgcn_s_setprio(0);
      // ---- causal mask ----
      if(s0 + KVB - 1 > P_ + q0w){
        #pragma unroll
        for(int mi = 0; mi < 4; ++mi){
          int qrow = q0w + mi*16 + lr;
          #pragma unroll
          for(int ni = 0; ni < 2; ++ni)
            #pragma unroll
            for(int r = 0; r < 4; ++r){
              int skey = s0 + ni*16 + lg*4 + r;
              if(skey > P_ + qrow) pacc[mi][ni][r] = -1e30f;
            }
        }
      }
      // ---- p = exp2(s - M): raw v_exp_f32, no max tracking, no rescale ----
      #pragma unroll
      for(int mi = 0; mi < 4; ++mi){
        float rs = 0.f;
        #pragma unroll
        for(int ni = 0; ni < 2; ++ni){
          float p0 = fexp2(pacc[mi][ni][0]);
          float p1 = fexp2(pacc[mi][ni][1]);
          float p2 = fexp2(pacc[mi][ni][2]);
          float p3 = fexp2(pacc[mi][ni][3]);
          rs += (p0 + p1) + (p2 + p3);
          uint2 pw; pw.x = pk2bf(p0, p1); pw.y = pk2bf(p2, p3);
          *(uint2*)(&Ps[w][(mi*16 + lr)*PSL + ni*16 + lg*4]) = pw;
        }
        l[mi] += rs;
      }
      // ---- PV: A = P rows=q, B = V^T cols=d (interleaved Vs layout) ----
      u16x8 pa[4];
      #pragma unroll
      for(int mi = 0; mi < 4; ++mi)
        pa[mi] = *(const u16x8*)(&Ps[w][(mi*16 + lr)*PSL + lg*8]);
      __builtin_amdgcn_s_setprio(1);
      #pragma unroll
      for(int ni = 0; ni < 8; ++ni){
        int d = ni*16 + lr;
        int voffr = ((d >> 1) << 6) + ((lg ^ gread) << 4) + ((d & 1) << 3);
        u16x8 vbf = *(const u16x8*)(&Vs[cur][voffr]);
        #pragma unroll
        for(int mi = 0; mi < 4; ++mi)
          o[mi][ni] = mfma16(pa[mi], vbf, o[mi][ni]);
      }
      __builtin_amdgcn_s_setprio(0);
    }
    __syncthreads();
  }
  // ---- epilogue: reduce l across lg, write partial o (bf16) and partial l ----
  int bh = b * H_ + h;
  #pragma unroll
  for(int mi = 0; mi < 4; ++mi){
    float lt = l[mi];
    lt += __shfl_xor(lt, 16);
    lt += __shfl_xor(lt, 32);
    #pragma unroll
    for(int r = 0; r < 4; ++r){
      int qrow = q0w + mi*16 + lg*4 + r;
      long obase = ((long)(sp*64 + bh) * Q_ + qrow) * 128;
      #pragma unroll
      for(int ni = 0; ni < 8; ++ni)
        po[obase + ni*16 + lr] = f2bf(o[mi][ni][r]);
    }
    if(lane < 16)
      pl[(sp*64 + bh) * Q_ + q0w + mi*16 + lane] = lt;
  }
}

// ---------------- combine: OH = (po0 + po1) / (pl0 + pl1), bf16 partials -----------------
__global__ __launch_bounds__(256) void combine(
    const unsigned short* __restrict__ po, const float* __restrict__ pl,
    unsigned short* __restrict__ OH){
  int idx = blockIdx.x * 256 + threadIdx.x;
  int row = idx >> 5;
  int d4 = (idx & 31) * 4;
  int bh = row >> 10, q = row & 1023;
  int b = bh >> 5, h = bh & 31;
  float lsum = pl[bh*1024 + q] + pl[65536 + bh*1024 + q];
  float inv = 1.0f / lsum;
  u16x4 a = *(const u16x4*)(po + (long)row*128 + d4);
  u16x4 c = *(const u16x4*)(po + 8388608L + (long)row*128 + d4);
  u16x4 r = { f2bf((bf2f(a[0]) + bf2f(c[0])) * inv), f2bf((bf2f(a[1]) + bf2f(c[1])) * inv),
              f2bf((bf2f(a[2]) + bf2f(c[2])) * inv), f2bf((bf2f(a[3]) + bf2f(c[3])) * inv) };
  *(u16x4*)(OH + ((long)(b*1024 + q))*4096 + h*128 + d4) = r;
}

extern "C" void kernel_launch(void* const* d_in, const int* in_sizes, int n_in,
                              void* d_out, int out_size, void* d_ws, size_t ws_size,
                              hipStream_t stream){
  const float* hs   = (const float*)d_in[0];
  const float* cosb = (const float*)d_in[1];
  const float* sinb = (const float*)d_in[2];
  const float* kc   = (const float*)d_in[3];
  const float* vc   = (const float*)d_in[4];
  const float* Wq   = (const float*)d_in[5];
  const float* Wk   = (const float*)d_in[6];
  const float* Wv   = (const float*)d_in[7];
  const float* Wo   = (const float*)d_in[8];
  const float* qw   = (const float*)d_in[9];
  const float* kw   = (const float*)d_in[10];
  char* ws = (char*)d_ws;
  // layout (bytes):
  // [0, 50.3M)        Craw fp32 (dead after pp) -> OH@0 (16.8M)
  // [50.3M, 117.4M)   WT qkv bf16 (dead after gemm) -> PO bf16 (33.6 MB)
  // [117.4M, 150.9M)  WoT bf16 (live until gemm_o)
  // [151.0M, 167.8M)  AH bf16 -> QB (after gemm_qkv)
  // [167.8M, 184.5M)  KB ; [184.5M, 201.3M) VT ; [201.3M, 201.9M) PL ; MW @202M
  float* Craw          = (float*)ws;
  unsigned short* OH   = (unsigned short*)ws;
  unsigned short* WT   = (unsigned short*)(ws + 50331648);
  unsigned short* PO   = (unsigned short*)(ws + 50331648);
  unsigned short* WoT  = (unsigned short*)(ws + 117440512);
  unsigned short* AH   = (unsigned short*)(ws + 150994944);
  unsigned short* QB   = (unsigned short*)(ws + 150994944);
  unsigned short* KB   = (unsigned short*)(ws + 167772160);
  unsigned short* VT   = (unsigned short*)(ws + 184549376);
  float* PL            = (float*)(ws + 201326592);
  float* MW            = (float*)(ws + 201981952);
  float* Out = (float*)d_out;

  prep_all<<<dim3(13057), dim3(256), 0, stream>>>(hs, kc, vc, qw, kw,
      Wq, Wk, Wv, Wo, AH, KB, VT, WT, WoT, MW);
  gemm_bf16<<<dim3(768), dim3(256), 0, stream>>>(AH, WT, Craw, 48, NQKV);
  pp_qkv<<<dim3(20480), dim3(256), 0, stream>>>(Craw, cosb, sinb, qw, kw, QB, KB, VT);
  attn<<<dim3(8, 32, 2), dim3(256), 0, stream>>>(QB, KB, VT, MW, PO, PL);
  combine<<<dim3(8192), dim3(256), 0, stream>>>(PO, PL, OH);
  gemm_bf16<<<dim3(512), dim3(256), 0, stream>>>(OH, WoT, Out, 32, 4096);
}

// Round 18
// 484.316 us; speedup vs baseline: 1.0310x; 1.0310x over previous
//
#include <hip/hip_runtime.h>
#include <hip/hip_bf16.h>

#define B_ 2
#define Q_ 1024
#define P_ 3072
#define HID_ 4096
#define H_ 32
#define KV_ 8
#define D_ 128
#define S_ 4096
#define NQKV 6144
// 1/sqrt(128) * log2(e)  (softmax runs in log2 domain)
#define QSCALE 0.1275174432f

typedef __attribute__((ext_vector_type(4))) float f32x4;
typedef __attribute__((ext_vector_type(8))) unsigned short u16x8;
typedef __attribute__((ext_vector_type(4))) unsigned short u16x4;
typedef __attribute__((ext_vector_type(8))) __bf16 bf16x8;

__device__ __forceinline__ unsigned short f2bf(float f){
  unsigned u = __builtin_bit_cast(unsigned, f);
  unsigned r = (u + 0x7FFFu + ((u >> 16) & 1u)) >> 16;
  return (unsigned short)r;
}
__device__ __forceinline__ float bf2f(unsigned short h){
  unsigned u = ((unsigned)h) << 16;
  return __builtin_bit_cast(float, u);
}
__device__ __forceinline__ unsigned pk2bf(float lo, float hi){
  unsigned r;
  asm("v_cvt_pk_bf16_f32 %0, %1, %2" : "=v"(r) : "v"(lo), "v"(hi));
  return r;
}
// raw-rate exp2: single v_exp_f32 (libm exp2f is a multi-instr ocml call)
__device__ __forceinline__ float fexp2(float x){
  float r; asm("v_exp_f32 %0, %1" : "=v"(r) : "v"(x)); return r;
}
__device__ __forceinline__ f32x4 mfma16(u16x8 a, u16x8 b, f32x4 c){
  return __builtin_amdgcn_mfma_f32_16x16x32_bf16(
      __builtin_bit_cast(bf16x8, a), __builtin_bit_cast(bf16x8, b), c, 0, 0, 0);
}
typedef const __attribute__((address_space(1))) void* gp1_t;
typedef __attribute__((address_space(3))) void* lp3_t;
__device__ __forceinline__ void gl16(const unsigned short* g, unsigned short* l){
  __builtin_amdgcn_global_load_lds((gp1_t)g, (lp3_t)l, 16, 0, 0);
}

// ---------------- setup: prep(hs,kc) + cache_vt(vc) + maxw in ONE launch -----------------
#define N1_ 2097152   // (B*Q*HID)/4
#define N2_ 1572864   // (B*KV*P*D)/4
__global__ __launch_bounds__(256) void setup(
    const float* __restrict__ hs, const float* __restrict__ kc,
    const float* __restrict__ vc, const float* __restrict__ qw,
    const float* __restrict__ kw, unsigned short* __restrict__ AH,
    unsigned short* __restrict__ Kb, unsigned short* __restrict__ VT,
    float* __restrict__ M){
  __shared__ unsigned short T[128][72];
  __shared__ float sa[4], sb[4];
  int bx = blockIdx.x;
  int tid = threadIdx.x;
  if(bx < 2048){
    const int PD = P_ * D_;
    const long SD = (long)S_ * D_;
    for(int i4 = bx * 256 + tid; i4 < N1_ + N2_; i4 += 2048 * 256){
      if(i4 < N1_){
        long i = (long)i4 * 4;
        float4 x = *(const float4*)(hs + i);
        *(u16x4*)(AH + i) = (u16x4){f2bf(x.x), f2bf(x.y), f2bf(x.z), f2bf(x.w)};
      } else {
        long i = (long)(i4 - N1_) * 4;
        int bkv = (int)(i / PD);
        int rem = (int)(i - (long)bkv * PD);
        long dst = (long)bkv * SD + rem;
        float4 k4 = *(const float4*)(kc + i);
        *(u16x4*)(Kb + dst) = (u16x4){f2bf(k4.x), f2bf(k4.y), f2bf(k4.z), f2bf(k4.w)};
      }
    }
  } else if(bx < 2816){
    int idx = bx - 2048;
    int bkv = idx / 48;
    int s0 = (idx % 48) * 64;
    int r = tid >> 2, dblk = (tid & 3) * 32;
    const float* src = vc + ((long)bkv * P_ + s0 + r) * 128 + dblk;
    #pragma unroll
    for(int u = 0; u < 8; ++u){
      float4 v = *(const float4*)(src + u*4);
      T[dblk + u*4 + 0][r] = f2bf(v.x);
      T[dblk + u*4 + 1][r] = f2bf(v.y);
      T[dblk + u*4 + 2][r] = f2bf(v.z);
      T[dblk + u*4 + 3][r] = f2bf(v.w);
    }
    __syncthreads();
    int d = tid >> 1, sh = (tid & 1) * 32;
    unsigned short* dst = VT + ((long)bkv * 128 + d) * S_ + s0 + sh;
    #pragma unroll
    for(int u = 0; u < 4; ++u){
      u16x8 v;
      #pragma unroll
      for(int j = 0; j < 8; ++j) v[j] = T[d][sh + u*8 + j];
      *(u16x8*)(dst + u*8) = v;
    }
  } else {
    float a = (tid < 128) ? fabsf(qw[tid]) : 0.f;
    float b = (tid < 128) ? fabsf(kw[tid]) : 0.f;
    #pragma unroll
    for(int o = 32; o; o >>= 1){
      a = fmaxf(a, __shfl_xor(a, o));
      b = fmaxf(b, __shfl_xor(b, o));
    }
    if((tid & 63) == 0){ sa[tid >> 6] = a; sb[tid >> 6] = b; }
    __syncthreads();
    if(tid == 0){
      float mq = fmaxf(fmaxf(sa[0], sa[1]), fmaxf(sa[2], sa[3]));
      float mk = fmaxf(fmaxf(sb[0], sb[1]), fmaxf(sb[2], sb[3]));
      M[0] = 128.0f * QSCALE * mq * mk * 1.01f + 0.25f;
    }
  }
}

// ---------------- convert all weights: Wq|Wk|Wv -> WT, Wo -> WoT (one launch) ------------
__global__ __launch_bounds__(256) void convert_w(
    const float* __restrict__ Wq, const float* __restrict__ Wk,
    const float* __restrict__ Wv, const float* __restrict__ Wo,
    unsigned short* __restrict__ WT, unsigned short* __restrict__ WoT){
  __shared__ float tile[64][65];
  int x = blockIdx.x;
  const float* W; int ldn, n_off; unsigned short* dst; int n0;
  if(x < 64)      { W = Wq; ldn = 4096; n_off = 0;    dst = WT;  n0 = x * 64; }
  else if(x < 80) { W = Wk; ldn = 1024; n_off = 4096; dst = WT;  n0 = (x-64) * 64; }
  else if(x < 96) { W = Wv; ldn = 1024; n_off = 5120; dst = WT;  n0 = (x-80) * 64; }
  else            { W = Wo; ldn = 4096; n_off = 0;    dst = WoT; n0 = (x-96) * 64; }
  int k0 = blockIdx.y * 64;
  int tid = threadIdx.x;
  int r = tid >> 4, c = (tid & 15) * 4;
  #pragma unroll
  for(int j = 0; j < 4; ++j){
    float4 v = *(const float4*)(W + (long)(k0 + r + j*16) * ldn + n0 + c);
    tile[r + j*16][c] = v.x; tile[r + j*16][c+1] = v.y;
    tile[r + j*16][c+2] = v.z; tile[r + j*16][c+3] = v.w;
  }
  __syncthreads();
  #pragma unroll
  for(int j = 0; j < 4; ++j){
    int n = r + j*16;
    long o = (long)(n_off + n0 + n) * 4096 + k0 + c;
    *(u16x4*)(dst + o) = (u16x4){f2bf(tile[c][n]), f2bf(tile[c+1][n]),
                                 f2bf(tile[c+2][n]), f2bf(tile[c+3][n])};
  }
}

// ---------------- single-plane bf16 GEMM (m97 structure, by-fastest L2 mapping) ----------
__global__ __launch_bounds__(256) void gemm_bf16(
    const unsigned short* __restrict__ Ag, const unsigned short* __restrict__ Bg,
    float* __restrict__ C, int nbx, int ldc){
  __shared__ __align__(16) unsigned short sA[4096], sB[4096];
  int tid = threadIdx.x;
  int nwg = nbx * 16;
  int lin = blockIdx.x;
  int cpx = nwg >> 3;
  int swz = (lin & 7) * cpx + (lin >> 3);   // XCD swizzle (nwg % 8 == 0)
  int by = swz & 15, bx = swz >> 4;         // by fastest: same-B blocks co-resident
  int m0 = by * 128, n0 = bx * 128;
  int lane = tid & 63, w = tid >> 6;
  int lr = lane & 15, lg = lane >> 4;
  int wm = (w >> 1) * 64, wn = (w & 1) * 64;
  int rowi = w * 16 + (lane >> 2);
  int cchunk = ((lane & 3) ^ ((lane >> 3) & 3)) << 3;
  const unsigned short* aP = Ag + (long)(m0 + rowi) * 4096 + cchunk;
  const unsigned short* bP = Bg + (long)(n0 + rowi) * 4096 + cchunk;
  const int step2 = 64 * 4096;
  unsigned short* dA = sA + w * 512;
  unsigned short* dB = sB + w * 512;
  int rdcol = (lg * 8) ^ (((lr >> 1) & 3) << 3);
  f32x4 zero = {0.f,0.f,0.f,0.f};
  f32x4 acc[4][4];
  #pragma unroll
  for(int mi=0;mi<4;++mi)
    #pragma unroll
    for(int ni=0;ni<4;++ni) acc[mi][ni] = zero;

  for(int kt = 0; kt < 128; ++kt){
    int kk = kt * 32;
    __syncthreads();
    gl16(aP + kk, dA);  gl16(aP + step2 + kk, dA + 2048);
    gl16(bP + kk, dB);  gl16(bP + step2 + kk, dB + 2048);
    __syncthreads();
    u16x8 ah[4];
    #pragma unroll
    for(int mi = 0; mi < 4; ++mi)
      ah[mi] = *(const u16x8*)(sA + (wm + mi*16 + lr) * 32 + rdcol);
    #pragma unroll
    for(int ni = 0; ni < 4; ++ni){
      u16x8 bh = *(const u16x8*)(sB + (wn + ni*16 + lr) * 32 + rdcol);
      #pragma unroll
      for(int mi = 0; mi < 4; ++mi)
        acc[mi][ni] = mfma16(ah[mi], bh, acc[mi][ni]);
    }
  }
  #pragma unroll
  for(int mi = 0; mi < 4; ++mi)
    #pragma unroll
    for(int r = 0; r < 4; ++r){
      long rowoff = (long)(m0 + wm + mi*16 + lg*4 + r) * ldc + n0 + wn + lr;
      #pragma unroll
      for(int ni = 0; ni < 4; ++ni)
        C[rowoff + ni*16] = acc[mi][ni][r];
    }
}

// ---------------- fused postprocess Q + KV (one launch) ----------------------------------
__global__ __launch_bounds__(256) void pp_qkv(
    const float* __restrict__ Craw, const float* __restrict__ cosb,
    const float* __restrict__ sinb, const float* __restrict__ qw,
    const float* __restrict__ kw, unsigned short* __restrict__ Qb,
    unsigned short* __restrict__ Kb, unsigned short* __restrict__ VT){
  int rid = blockIdx.x * 4 + (threadIdx.x >> 6);
  int lane = threadIdx.x & 63;
  if(rid < 65536){
    int b = rid >> 15;
    int rem = rid & 32767;
    int q = rem >> 5;
    int h = rem & 31;
    long rowoff = (long)(b * Q_ + q) * NQKV + h * 128;
    float x1 = Craw[rowoff + lane];
    float x2 = Craw[rowoff + 64 + lane];
    float ss = x1*x1 + x2*x2;
    for(int o = 32; o; o >>= 1) ss += __shfl_xor(ss, o);
    float norm = rsqrtf(ss * (1.0f/128.0f) + 1e-6f);
    float xn1 = x1 * norm * qw[lane];
    float xn2 = x2 * norm * qw[64 + lane];
    long co = (long)(b * Q_ + q) * 128;
    float c1 = cosb[co + lane],      s1 = sinb[co + lane];
    float c2 = cosb[co + 64 + lane], s2 = sinb[co + 64 + lane];
    float o1 = (xn1 * c1 - xn2 * s1) * QSCALE;
    float o2 = (xn2 * c2 + xn1 * s2) * QSCALE;
    long dst = ((long)(b * H_ + h) * Q_ + q) * 128;
    Qb[dst + lane] = f2bf(o1);
    Qb[dst + 64 + lane] = f2bf(o2);
  } else {
    int rid2 = rid - 65536;
    int b = rid2 >> 13;
    int rem = rid2 & 8191;
    int q = rem >> 3;
    int kv = rem & 7;
    int bkv = b * KV_ + kv;
    long rowoff = (long)(b * Q_ + q) * NQKV;
    float x1 = Craw[rowoff + 4096 + kv*128 + lane];
    float x2 = Craw[rowoff + 4096 + kv*128 + 64 + lane];
    float ss = x1*x1 + x2*x2;
    for(int o = 32; o; o >>= 1) ss += __shfl_xor(ss, o);
    float norm = rsqrtf(ss * (1.0f/128.0f) + 1e-6f);
    float xn1 = x1 * norm * kw[lane];
    float xn2 = x2 * norm * kw[64 + lane];
    long co = (long)(b * Q_ + q) * 128;
    float c1 = cosb[co + lane],      s1 = sinb[co + lane];
    float c2 = cosb[co + 64 + lane], s2 = sinb[co + 64 + lane];
    long dst = ((long)bkv * S_ + P_ + q) * 128;
    Kb[dst + lane]      = f2bf(xn1 * c1 - xn2 * s1);
    Kb[dst + 64 + lane] = f2bf(xn2 * c2 + xn1 * s2);
    float v1 = Craw[rowoff + 5120 + kv*128 + lane];
    float v2 = Craw[rowoff + 5120 + kv*128 + 64 + lane];
    VT[((long)bkv * 128 + lane) * S_ + P_ + q]      = f2bf(v1);
    VT[((long)bkv * 128 + 64 + lane) * S_ + P_ + q] = f2bf(v2);
  }
}

// ---------------- flash attention: fixed-max, 64 q/wave, QBLK=256, ksplit x2 -------------
// Round-13 proven body; partials stored as bf16 (halves partial-O HBM traffic).
#define KVB 32
#define PSL 40
__global__ __launch_bounds__(256, 2) void attn(
    const unsigned short* __restrict__ Qg, const unsigned short* __restrict__ Kg,
    const unsigned short* __restrict__ VTg, const float* __restrict__ Mp,
    unsigned short* __restrict__ po, float* __restrict__ pl){
  __shared__ __align__(16) unsigned short Ks[2][KVB*128];
  __shared__ __align__(16) unsigned short Vs[2][128*KVB];
  __shared__ __align__(16) unsigned short Ps[4][64*PSL];
  int tid = threadIdx.x;
  int qb = blockIdx.x >> 1, sp = blockIdx.x & 1;
  int b = blockIdx.z, h = blockIdx.y, q0 = qb * 256;
  int kvh = h >> 2;
  int w = tid >> 6, lane = tid & 63, lr = lane & 15, lg = lane >> 4;
  int q0w = q0 + w * 64;
  float Mv = Mp[0];
  u16x8 qh[4][4];
  #pragma unroll
  for(int mi = 0; mi < 4; ++mi){
    long qbase = ((long)(b * H_ + h) * Q_ + q0w + mi*16 + lr) * 128;
    #pragma unroll
    for(int c = 0; c < 4; ++c)
      qh[mi][c] = *(const u16x8*)(Qg + qbase + c*32 + lg*8);
  }
  f32x4 minit = {-Mv, -Mv, -Mv, -Mv};
  f32x4 o[4][8];
  #pragma unroll
  for(int mi = 0; mi < 4; ++mi)
    #pragma unroll
    for(int i = 0; i < 8; ++i) o[mi][i] = (f32x4){0.f,0.f,0.f,0.f};
  float l[4] = {0.f, 0.f, 0.f, 0.f};
  long kb  = (long)(b * KV_ + kvh) * S_ * 128;
  long vb0 = (long)(b * KV_ + kvh) * 128 * (long)S_;
  int T = 104 + 8 * qb;
  int half = T >> 1;
  int t0 = sp ? half : 0;
  int t1 = sp ? T : half;
  int koff[2], voff[2], ldst[2];
  #pragma unroll
  for(int i = 0; i < 2; ++i){
    int L = (w*2 + i)*64 + lane;
    ldst[i] = L * 8;
    int r = L >> 4, c8 = (L & 15) ^ (r & 7);
    koff[i] = r*128 + c8*8;
    // V slot L -> d-pair interleave: d = (L>>3)*2 + (L&1), mem-chunk = (L>>1)&3
    int d = ((L >> 3) << 1) | (L & 1);
    int sm = (L >> 1) & 3;
    int g = (d & 3) ^ ((d >> 2) & 3);
    voff[i] = d * S_ + ((sm ^ g) << 3);
  }
  {
    const unsigned short* kg = Kg + kb + (long)t0 * (KVB*128);
    const unsigned short* vg = VTg + vb0 + t0 * KVB;
    #pragma unroll
    for(int i = 0; i < 2; ++i){
      gl16(kg + koff[i], &Ks[t0 & 1][ldst[i]]);
      gl16(vg + voff[i], &Vs[t0 & 1][ldst[i]]);
    }
  }
  __syncthreads();

  int lr7 = lr & 7;
  int gread = (lr & 3) ^ ((lr >> 2) & 3);   // g(d) for d = ni*16+lr (ni-independent)
  for(int t = t0; t < t1; ++t){
    int cur = t & 1;
    if(t + 1 < t1){
      int s1 = (t + 1) * KVB;
      const unsigned short* kg = Kg + kb + (long)s1 * 128;
      const unsigned short* vg = VTg + vb0 + s1;
      #pragma unroll
      for(int i = 0; i < 2; ++i){
        gl16(kg + koff[i], &Ks[cur^1][ldst[i]]);
        gl16(vg + voff[i], &Vs[cur^1][ldst[i]]);
      }
    }
    int s0 = t * KVB;
    if(s0 <= P_ + q0w + 63){
      // ---- QK^T (swapped): D[key][q], q = lr per lane ----
      f32x4 pacc[4][2];
      #pragma unroll
      for(int mi = 0; mi < 4; ++mi){ pacc[mi][0] = minit; pacc[mi][1] = minit; }
      __builtin_amdgcn_s_setprio(1);
      #pragma unroll
      for(int c = 0; c < 4; ++c)
        #pragma unroll
        for(int ni = 0; ni < 2; ++ni){
          u16x8 kh = *(const u16x8*)(&Ks[cur][(ni*16 + lr)*128 + (((c*4 + lg) ^ lr7) << 3)]);
          #pragma unroll
          for(int mi = 0; mi < 4; ++mi)
            pacc[mi][ni] = mfma16(kh, qh[mi][c], pacc[mi][ni]);
        }
      __builtin_amdgcn_s_setprio(0);
      // ---- causal mask ----
      if(s0 + KVB - 1 > P_ + q0w){
        #pragma unroll
        for(int mi = 0; mi < 4; ++mi){
          int qrow = q0w + mi*16 + lr;
          #pragma unroll
          for(int ni = 0; ni < 2; ++ni)
            #pragma unroll
            for(int r = 0; r < 4; ++r){
              int skey = s0 + ni*16 + lg*4 + r;
              if(skey > P_ + qrow) pacc[mi][ni][r] = -1e30f;
            }
        }
      }
      // ---- p = exp2(s - M): raw v_exp_f32, no max tracking, no rescale ----
      #pragma unroll
      for(int mi = 0; mi < 4; ++mi){
        float rs = 0.f;
        #pragma unroll
        for(int ni = 0; ni < 2; ++ni){
          float p0 = fexp2(pacc[mi][ni][0]);
          float p1 = fexp2(pacc[mi][ni][1]);
          float p2 = fexp2(pacc[mi][ni][2]);
          float p3 = fexp2(pacc[mi][ni][3]);
          rs += (p0 + p1) + (p2 + p3);
          uint2 pw; pw.x = pk2bf(p0, p1); pw.y = pk2bf(p2, p3);
          *(uint2*)(&Ps[w][(mi*16 + lr)*PSL + ni*16 + lg*4]) = pw;
        }
        l[mi] += rs;
      }
      // ---- PV: A = P rows=q, B = V^T cols=d (interleaved Vs layout) ----
      u16x8 pa[4];
      #pragma unroll
      for(int mi = 0; mi < 4; ++mi)
        pa[mi] = *(const u16x8*)(&Ps[w][(mi*16 + lr)*PSL + lg*8]);
      __builtin_amdgcn_s_setprio(1);
      #pragma unroll
      for(int ni = 0; ni < 8; ++ni){
        int d = ni*16 + lr;
        int voffr = ((d >> 1) << 6) + ((lg ^ gread) << 4) + ((d & 1) << 3);
        u16x8 vbf = *(const u16x8*)(&Vs[cur][voffr]);
        #pragma unroll
        for(int mi = 0; mi < 4; ++mi)
          o[mi][ni] = mfma16(pa[mi], vbf, o[mi][ni]);
      }
      __builtin_amdgcn_s_setprio(0);
    }
    __syncthreads();
  }
  // ---- epilogue: reduce l across lg, write partial o (bf16) and partial l ----
  int bh = b * H_ + h;
  #pragma unroll
  for(int mi = 0; mi < 4; ++mi){
    float lt = l[mi];
    lt += __shfl_xor(lt, 16);
    lt += __shfl_xor(lt, 32);
    #pragma unroll
    for(int r = 0; r < 4; ++r){
      int qrow = q0w + mi*16 + lg*4 + r;
      long obase = ((long)(sp*64 + bh) * Q_ + qrow) * 128;
      #pragma unroll
      for(int ni = 0; ni < 8; ++ni)
        po[obase + ni*16 + lr] = f2bf(o[mi][ni][r]);
    }
    if(lane < 16)
      pl[(sp*64 + bh) * Q_ + q0w + mi*16 + lane] = lt;
  }
}

// ---------------- combine: OH = (po0 + po1) / (pl0 + pl1), bf16 partials -----------------
__global__ __launch_bounds__(256) void combine(
    const unsigned short* __restrict__ po, const float* __restrict__ pl,
    unsigned short* __restrict__ OH){
  int idx = blockIdx.x * 256 + threadIdx.x;   // 2,097,152 total
  int row = idx >> 5;
  int d4 = (idx & 31) * 4;
  int bh = row >> 10, q = row & 1023;
  int b = bh >> 5, h = bh & 31;
  float lsum = pl[bh*1024 + q] + pl[65536 + bh*1024 + q];
  float inv = 1.0f / lsum;
  u16x4 a = *(const u16x4*)(po + (long)row*128 + d4);
  u16x4 c = *(const u16x4*)(po + 8388608L + (long)row*128 + d4);
  u16x4 r = { f2bf((bf2f(a[0]) + bf2f(c[0])) * inv), f2bf((bf2f(a[1]) + bf2f(c[1])) * inv),
              f2bf((bf2f(a[2]) + bf2f(c[2])) * inv), f2bf((bf2f(a[3]) + bf2f(c[3])) * inv) };
  *(u16x4*)(OH + ((long)(b*1024 + q))*4096 + h*128 + d4) = r;
}

extern "C" void kernel_launch(void* const* d_in, const int* in_sizes, int n_in,
                              void* d_out, int out_size, void* d_ws, size_t ws_size,
                              hipStream_t stream){
  const float* hs   = (const float*)d_in[0];
  const float* cosb = (const float*)d_in[1];
  const float* sinb = (const float*)d_in[2];
  const float* kc   = (const float*)d_in[3];
  const float* vc   = (const float*)d_in[4];
  const float* Wq   = (const float*)d_in[5];
  const float* Wk   = (const float*)d_in[6];
  const float* Wv   = (const float*)d_in[7];
  const float* Wo   = (const float*)d_in[8];
  const float* qw   = (const float*)d_in[9];
  const float* kw   = (const float*)d_in[10];
  char* ws = (char*)d_ws;
  // layout (bytes):
  // [0, 50.3M)        Craw fp32 (dead after pp) -> OH@0 (16.8M)
  // [50.3M, 117.4M)   WT qkv bf16 (dead after gemm_qkv) -> PO bf16 (33.6 MB)
  // [117.4M, 150.9M)  WoT bf16 (live until gemm_o)
  // [151.0M, 167.8M)  AH bf16 -> QB (after gemm_qkv)
  // [167.8M, 184.5M)  KB ; [184.5M, 201.3M) VT ; [201.3M, 201.9M) PL ; MW @202M
  float* Craw          = (float*)ws;
  unsigned short* OH   = (unsigned short*)ws;
  unsigned short* WT   = (unsigned short*)(ws + 50331648);
  unsigned short* PO   = (unsigned short*)(ws + 50331648);
  unsigned short* WoT  = (unsigned short*)(ws + 117440512);
  unsigned short* AH   = (unsigned short*)(ws + 150994944);
  unsigned short* QB   = (unsigned short*)(ws + 150994944);
  unsigned short* KB   = (unsigned short*)(ws + 167772160);
  unsigned short* VT   = (unsigned short*)(ws + 184549376);
  float* PL            = (float*)(ws + 201326592);
  float* MW            = (float*)(ws + 201981952);
  float* Out = (float*)d_out;

  setup<<<dim3(2817), dim3(256), 0, stream>>>(hs, kc, vc, qw, kw, AH, KB, VT, MW);
  convert_w<<<dim3(160, 64), dim3(256), 0, stream>>>(Wq, Wk, Wv, Wo, WT, WoT);
  gemm_bf16<<<dim3(768), dim3(256), 0, stream>>>(AH, WT, Craw, 48, NQKV);
  pp_qkv<<<dim3(20480), dim3(256), 0, stream>>>(Craw, cosb, sinb, qw, kw, QB, KB, VT);
  attn<<<dim3(8, 32, 2), dim3(256), 0, stream>>>(QB, KB, VT, MW, PO, PL);
  combine<<<dim3(8192), dim3(256), 0, stream>>>(PO, PL, OH);
  gemm_bf16<<<dim3(512), dim3(256), 0, stream>>>(OH, WoT, Out, 32, 4096);
}